// Round 1
// baseline (453.548 us; speedup 1.0000x reference)
//
#include <hip/hip_runtime.h>

// XNOR binary linear: y = (sign(x) @ sign(W)^T) * scale
// N=262144 rows, IN=256, OUT=256, all fp32.
//
// Strategy: memory-bound (512 MB min traffic -> ~81us floor @6.3TB/s).
// Pack signs to bits; dot = 256 - 2*popcount(xor). Bit ordering: word s
// (s=0..3), bit l (lane) <-> element 4l+s of the 256-long vector. Both the
// weight pack kernel and the x ballot use this same ordering, so it cancels.
//
// Main kernel: zero LDS, zero barriers. One wave per 64-row chunk; per row:
// coalesced float4 load (1KB/wave), 4 ballots (SGPR masks), lane l computes
// output cols 4l..4l+3 from register-resident weight bits, coalesced float4
// store (1KB/wave). 1-deep prefetch of next row for latency hiding.

#define N_ROWS 262144
#define IN_DIM 256
#define OUT_DIM 256
#define ROWS_PER_WAVE 64

typedef unsigned long long u64;

__global__ void pack_weights(const float* __restrict__ w, u64* __restrict__ wb) {
    const int o = blockIdx.x;          // output channel 0..255
    const int l = threadIdx.x;         // lane 0..63
    const float4 f = ((const float4*)(w + (size_t)o * IN_DIM))[l];
    u64 b0 = __ballot(f.x < 0.0f);
    u64 b1 = __ballot(f.y < 0.0f);
    u64 b2 = __ballot(f.z < 0.0f);
    u64 b3 = __ballot(f.w < 0.0f);
    if (l == 0) {
        wb[o * 4 + 0] = b0;
        wb[o * 4 + 1] = b1;
        wb[o * 4 + 2] = b2;
        wb[o * 4 + 3] = b3;
    }
}

__global__ void __launch_bounds__(256, 4) bin_linear(
    const float* __restrict__ x, const u64* __restrict__ wb,
    const float* __restrict__ scale, float* __restrict__ out)
{
    const int l  = threadIdx.x & 63;   // lane
    const int wv = threadIdx.x >> 6;   // wave within block (0..3)
    const int gw = blockIdx.x * 4 + wv;  // global wave id

    // Weight bits for this lane's 4 output columns (cols 4l..4l+3), 16 u64 in regs.
    u64 W[4][4];
#pragma unroll
    for (int j = 0; j < 4; ++j) {
#pragma unroll
        for (int s = 0; s < 4; ++s) {
            W[j][s] = wb[(size_t)(4 * l + j) * 4 + s];
        }
    }
    const float4 sc = ((const float4*)scale)[l];

    const int row0 = gw * ROWS_PER_WAVE;
    const float4* xp = (const float4*)(x + (size_t)row0 * IN_DIM) + l;
    float4*       op = (float4*)(out + (size_t)row0 * IN_DIM) + l;

    float4 cur = *xp;
#pragma unroll 4
    for (int i = 0; i < ROWS_PER_WAVE; ++i) {
        float4 nxt = cur;
        if (i + 1 < ROWS_PER_WAVE) nxt = xp[(i + 1) * (IN_DIM / 4)];

        const u64 b0 = __ballot(cur.x < 0.0f);
        const u64 b1 = __ballot(cur.y < 0.0f);
        const u64 b2 = __ballot(cur.z < 0.0f);
        const u64 b3 = __ballot(cur.w < 0.0f);

        float4 o4;
        {
            int h = __builtin_popcountll(b0 ^ W[0][0]) + __builtin_popcountll(b1 ^ W[0][1])
                  + __builtin_popcountll(b2 ^ W[0][2]) + __builtin_popcountll(b3 ^ W[0][3]);
            o4.x = (float)(IN_DIM - 2 * h) * sc.x;
        }
        {
            int h = __builtin_popcountll(b0 ^ W[1][0]) + __builtin_popcountll(b1 ^ W[1][1])
                  + __builtin_popcountll(b2 ^ W[1][2]) + __builtin_popcountll(b3 ^ W[1][3]);
            o4.y = (float)(IN_DIM - 2 * h) * sc.y;
        }
        {
            int h = __builtin_popcountll(b0 ^ W[2][0]) + __builtin_popcountll(b1 ^ W[2][1])
                  + __builtin_popcountll(b2 ^ W[2][2]) + __builtin_popcountll(b3 ^ W[2][3]);
            o4.z = (float)(IN_DIM - 2 * h) * sc.z;
        }
        {
            int h = __builtin_popcountll(b0 ^ W[3][0]) + __builtin_popcountll(b1 ^ W[3][1])
                  + __builtin_popcountll(b2 ^ W[3][2]) + __builtin_popcountll(b3 ^ W[3][3]);
            o4.w = (float)(IN_DIM - 2 * h) * sc.w;
        }

        op[i * (IN_DIM / 4)] = o4;
        cur = nxt;
    }
}

extern "C" void kernel_launch(void* const* d_in, const int* in_sizes, int n_in,
                              void* d_out, int out_size, void* d_ws, size_t ws_size,
                              hipStream_t stream) {
    const float* x     = (const float*)d_in[0];   // [N, 256]
    const float* wgt   = (const float*)d_in[1];   // [256, 256]
    const float* scale = (const float*)d_in[2];   // [1, 256]
    float* out = (float*)d_out;                   // [N, 256]
    u64* wb = (u64*)d_ws;                         // 256*4 u64 = 8 KB packed weight bits

    pack_weights<<<OUT_DIM, 64, 0, stream>>>(wgt, wb);
    bin_linear<<<N_ROWS / 256, 256, 0, stream>>>(x, wb, scale, out);
}

// Round 2
// 432.649 us; speedup vs baseline: 1.0483x; 1.0483x over previous
//
#include <hip/hip_runtime.h>

// XNOR binary linear: y = (sign(x) @ sign(W)^T) * scale
// N=262144 rows, IN=256, OUT=256, all fp32.
//
// Memory-bound: 537 MB mandatory traffic (read x 268MB + write y 268MB)
// -> ~85us floor @ 6.3 TB/s. R1 measured <163us with 1-deep prefetch;
// theory: latency-bound (only ~1KB outstanding/wave, serial
// load->ballot->popcnt->store chain). This round: branch-free 4-deep
// register pipeline (4KB outstanding/wave, 64KB/CU >> 9.2KB Little's-law
// requirement), 32 rows/wave, nontemporal streaming loads/stores.
//
// Bit ordering: word s (s=0..3), bit l (lane) <-> element 4l+s. Same
// ordering in pack_weights (ballot) and bin_linear (ballot) -> cancels in
// the hamming distance. dot = 256 - 2*popcount(xb ^ wb), exact in fp32.

#define N_ROWS 262144
#define IN_DIM 256
#define OUT_DIM 256
#define ROWS_PER_WAVE 32
#define PIPE 4

typedef unsigned long long u64;
typedef float f32x4 __attribute__((ext_vector_type(4)));

__global__ void pack_weights(const float* __restrict__ w, u64* __restrict__ wb) {
    const int o = blockIdx.x;          // output channel 0..255
    const int l = threadIdx.x;         // lane 0..63
    const float4 f = ((const float4*)(w + (size_t)o * IN_DIM))[l];
    u64 b0 = __ballot(f.x < 0.0f);
    u64 b1 = __ballot(f.y < 0.0f);
    u64 b2 = __ballot(f.z < 0.0f);
    u64 b3 = __ballot(f.w < 0.0f);
    if (l == 0) {
        wb[o * 4 + 0] = b0;
        wb[o * 4 + 1] = b1;
        wb[o * 4 + 2] = b2;
        wb[o * 4 + 3] = b3;
    }
}

__device__ __forceinline__ f32x4 row_dot(f32x4 cur, const u64 W[4][4], f32x4 sc) {
    const u64 b0 = __ballot(cur.x < 0.0f);
    const u64 b1 = __ballot(cur.y < 0.0f);
    const u64 b2 = __ballot(cur.z < 0.0f);
    const u64 b3 = __ballot(cur.w < 0.0f);
    f32x4 o4;
    {
        int h = __builtin_popcountll(b0 ^ W[0][0]) + __builtin_popcountll(b1 ^ W[0][1])
              + __builtin_popcountll(b2 ^ W[0][2]) + __builtin_popcountll(b3 ^ W[0][3]);
        o4.x = (float)(IN_DIM - 2 * h) * sc.x;
    }
    {
        int h = __builtin_popcountll(b0 ^ W[1][0]) + __builtin_popcountll(b1 ^ W[1][1])
              + __builtin_popcountll(b2 ^ W[1][2]) + __builtin_popcountll(b3 ^ W[1][3]);
        o4.y = (float)(IN_DIM - 2 * h) * sc.y;
    }
    {
        int h = __builtin_popcountll(b0 ^ W[2][0]) + __builtin_popcountll(b1 ^ W[2][1])
              + __builtin_popcountll(b2 ^ W[2][2]) + __builtin_popcountll(b3 ^ W[2][3]);
        o4.z = (float)(IN_DIM - 2 * h) * sc.z;
    }
    {
        int h = __builtin_popcountll(b0 ^ W[3][0]) + __builtin_popcountll(b1 ^ W[3][1])
              + __builtin_popcountll(b2 ^ W[3][2]) + __builtin_popcountll(b3 ^ W[3][3]);
        o4.w = (float)(IN_DIM - 2 * h) * sc.w;
    }
    return o4;
}

__global__ void __launch_bounds__(256, 4) bin_linear(
    const float* __restrict__ x, const u64* __restrict__ wb,
    const float* __restrict__ scale, float* __restrict__ out)
{
    const int l  = threadIdx.x & 63;     // lane
    const int wv = threadIdx.x >> 6;     // wave within block (0..3)
    const int gw = blockIdx.x * 4 + wv;  // global wave id

    // Weight bits for this lane's 4 output columns (cols 4l..4l+3): 16 u64 in regs.
    u64 W[4][4];
#pragma unroll
    for (int j = 0; j < 4; ++j)
#pragma unroll
        for (int s = 0; s < 4; ++s)
            W[j][s] = wb[(size_t)(4 * l + j) * 4 + s];

    const f32x4 sc = ((const f32x4*)scale)[l];

    const int row0 = gw * ROWS_PER_WAVE;
    const f32x4* xp = (const f32x4*)(x + (size_t)row0 * IN_DIM) + l;
    f32x4*       op = (f32x4*)(out + (size_t)row0 * IN_DIM) + l;
    const int rstride = IN_DIM / 4;      // float4s per row

    // 4-deep branch-free software pipeline.
    f32x4 buf[PIPE];
#pragma unroll
    for (int p = 0; p < PIPE; ++p)
        buf[p] = __builtin_nontemporal_load(&xp[p * rstride]);

#pragma unroll 4
    for (int i = 0; i < ROWS_PER_WAVE - PIPE; ++i) {
        f32x4 cur = buf[i & (PIPE - 1)];
        buf[i & (PIPE - 1)] = __builtin_nontemporal_load(&xp[(i + PIPE) * rstride]);
        __builtin_nontemporal_store(row_dot(cur, W, sc), &op[i * rstride]);
    }
#pragma unroll
    for (int i = ROWS_PER_WAVE - PIPE; i < ROWS_PER_WAVE; ++i) {
        __builtin_nontemporal_store(row_dot(buf[i & (PIPE - 1)], W, sc), &op[i * rstride]);
    }
}

extern "C" void kernel_launch(void* const* d_in, const int* in_sizes, int n_in,
                              void* d_out, int out_size, void* d_ws, size_t ws_size,
                              hipStream_t stream) {
    const float* x     = (const float*)d_in[0];   // [N, 256]
    const float* wgt   = (const float*)d_in[1];   // [256, 256]
    const float* scale = (const float*)d_in[2];   // [1, 256]
    float* out = (float*)d_out;                   // [N, 256]
    u64* wb = (u64*)d_ws;                         // 256*4 u64 = 8 KB packed weight bits

    pack_weights<<<OUT_DIM, 64, 0, stream>>>(wgt, wb);
    bin_linear<<<N_ROWS / (4 * ROWS_PER_WAVE), 256, 0, stream>>>(x, wb, scale, out);
}